// Round 11
// baseline (243.319 us; speedup 1.0000x reference)
//
#include <hip/hip_runtime.h>
#include <hip/hip_bf16.h>

#define SB 2048   // sequence
#define DM 1024   // model dim
#define NH 16     // heads
#define HD 64     // head dim
#define BB 4      // batch
#define MTOT (BB * SB)   // 8192 rows
#define NW (DM * DM)
#define QSCALE 0.1803368801111244f   // 0.125 * log2(e): scores in log2 domain

typedef __attribute__((ext_vector_type(8))) short bf16x8;
typedef __attribute__((ext_vector_type(4))) short bf16x4;
typedef __attribute__((ext_vector_type(4))) float f32x4;
typedef __attribute__((ext_vector_type(8))) __fp16 f16x8;
typedef __attribute__((ext_vector_type(4))) __fp16 f16x4;
typedef __attribute__((ext_vector_type(2))) __fp16 f16x2;

__device__ __forceinline__ short f2bf(float f) {
    union { float f; unsigned u; } a; a.f = f;
    unsigned r = (a.u + 0x7FFF + ((a.u >> 16) & 1)) >> 16;
    return (short)r;
}

// ---------------------------------------------------------------------------
// Fused input conversion: bid<4096 -> x fp32->bf16 (8 elem/thread);
// else weight transpose+cast (64x64 LDS tiles): Wq/Wk/Wv [1024][64]->
// [64][1024] stacked into wall, Wo [1024][1024] -> wot^T.
// ---------------------------------------------------------------------------
__global__ __launch_bounds__(256) void cvt_all(const float* __restrict__ x,
                                               const float* __restrict__ Wq,
                                               const float* __restrict__ Wk,
                                               const float* __restrict__ Wv,
                                               const float* __restrict__ Wo,
                                               short* __restrict__ xb,
                                               short* __restrict__ wall,
                                               short* __restrict__ wot) {
    const int bid = blockIdx.x;
    const int t = threadIdx.x;
    if (bid < 4096) {
        const int i = (bid * 256 + t) * 8;
        float4 v0 = *(const float4*)(x + i);
        float4 v1 = *(const float4*)(x + i + 4);
        bf16x8 o = { f2bf(v0.x), f2bf(v0.y), f2bf(v0.z), f2bf(v0.w),
                     f2bf(v1.x), f2bf(v1.y), f2bf(v1.z), f2bf(v1.w) };
        *(bf16x8*)(xb + i) = o;
        return;
    }
    __shared__ float Ls[64][65];
    const int rem = bid - 4096;
    const int which = rem >> 8;
    const int rem2 = rem & 255;
    const float* in;
    short* out;
    int R, C;
    if (which < 3) {
        in = (which == 0) ? Wq : (which == 1) ? Wk : Wv;
        out = wall + (size_t)which * NW;
        R = DM; C = HD;
    } else {
        in = Wo; out = wot; R = DM; C = DM;
    }
    const int tilesC = C >> 6, tilesR = R >> 6;
    const int b = rem2 / (tilesR * tilesC);
    const int rr = rem2 % (tilesR * tilesC);
    const int R0 = (rr / tilesC) << 6;
    const int C0 = (rr % tilesC) << 6;
    const float* src = in + (size_t)b * R * C;
    short* dst = out + (size_t)b * R * C;
    const int r = t >> 2, c4 = (t & 3) << 4;
    const float* p = src + (size_t)(R0 + r) * C + C0 + c4;
#pragma unroll
    for (int u = 0; u < 16; u += 4) {
        float4 v = *(const float4*)(p + u);
        Ls[r][c4 + u] = v.x; Ls[r][c4 + u + 1] = v.y;
        Ls[r][c4 + u + 2] = v.z; Ls[r][c4 + u + 3] = v.w;
    }
    __syncthreads();
    const int cc = t >> 2, u2 = (t & 3) << 4;
    short* q = dst + (size_t)(C0 + cc) * R + R0 + u2;
    bf16x8 o0, o1;
#pragma unroll
    for (int j = 0; j < 8; ++j) o0[j] = f2bf(Ls[u2 + j][cc]);
#pragma unroll
    for (int j = 0; j < 8; ++j) o1[j] = f2bf(Ls[u2 + 8 + j][cc]);
    *(bf16x8*)(q) = o0;
    *(bf16x8*)(q + 8) = o1;
}

// ---------------------------------------------------------------------------
// bf16 MFMA GEMM, BK=64 (16 K-steps): 128x128 tile, 4 waves x 4x4 MFMA x2
// halves per step. LDS XOR-swizzled in 16B chunks: LDS chunk c of row r
// holds GLOBAL chunk c^(r&7); swizzle applied on the GLOBAL SOURCE pointer
// (global_load_lds dst must be wave-uniform base + lane*16).
// MODE 0: fused QKV (A @ WAll[3072][1024]^T), block-uniform branch on n0:
//   n0<2048 (QK): C^T orientation -> q(*QSCALE)/k bf16 [b,h,s,d] bf16x4
//   n0>=2048 (V): C orientation  -> vT f16 [b,h,d,s'] f16x4, where s' is
//   the PV-fragment permutation: within each 32-s block,
//   s' = ((s>>2)&3)*8 + ((s>>4)&1)*4 + (s&3)  (quad*8 + parity*4 + j).
//   This makes attn's two adjacent-st V fragments one contiguous 16B chunk.
// MODE 1: out-projection, C^T orientation, float4 -> fp32 [M][DM].
// ---------------------------------------------------------------------------
template <int MODE>
__global__ __launch_bounds__(256) void mm64(const short* __restrict__ A,
                                            const short* __restrict__ BT,
                                            short* __restrict__ qO,
                                            short* __restrict__ kO,
                                            _Float16* __restrict__ vO,
                                            float* __restrict__ fO) {
    __shared__ short sA[128 * 64];
    __shared__ short sB[128 * 64];
    const int t = threadIdx.x;
    const int lane = t & 63;
    const int w = t >> 6;
    const int wm = w >> 1, wn = w & 1;
    const int l15 = lane & 15, quad = lane >> 4;
    const int m0 = blockIdx.x * 128;
    const int n0 = blockIdx.y * 128;
    const bool isV = (MODE == 0) && (n0 >= 2048);

    f32x4 acc[4][4] = {};
    const int srow = t >> 3;                        // 0..31 (+32 per u)
    const int schunk = t & 7;
    const int ssrc = ((schunk ^ (srow & 7)) << 3);  // swizzled GLOBAL chunk
    const int sdst = (schunk << 3);                 // linear LDS chunk
    const int r7 = l15 & 7;                         // reader XOR key

    for (int k0 = 0; k0 < DM; k0 += 64) {
#pragma unroll
        for (int u = 0; u < 4; ++u) {
            const int row = u * 32 + srow;          // row&7 == srow&7
            const short* ga = A + (size_t)(m0 + row) * DM + k0 + ssrc;
            const short* gb = BT + (size_t)(n0 + row) * DM + k0 + ssrc;
            __builtin_amdgcn_global_load_lds(
                (const __attribute__((address_space(1))) unsigned*)ga,
                (__attribute__((address_space(3))) unsigned*)&sA[(row << 6) + sdst],
                16, 0, 0);
            __builtin_amdgcn_global_load_lds(
                (const __attribute__((address_space(1))) unsigned*)gb,
                (__attribute__((address_space(3))) unsigned*)&sB[(row << 6) + sdst],
                16, 0, 0);
        }
        __syncthreads();

#pragma unroll
        for (int half = 0; half < 2; ++half) {
            bf16x8 af[4], bfr[4];
#pragma unroll
            for (int i = 0; i < 4; ++i) {
                const int ra = wm * 64 + i * 16 + l15;
                const int rb = wn * 64 + i * 16 + l15;
                const int ch = ((half * 4 + quad) ^ r7) << 3;   // ra&7 == r7
                af[i]  = *(const bf16x8*)&sA[(ra << 6) + ch];
                bfr[i] = *(const bf16x8*)&sB[(rb << 6) + ch];
            }
            if (isV) {
#pragma unroll
                for (int i = 0; i < 4; ++i)
#pragma unroll
                    for (int j = 0; j < 4; ++j)
                        acc[i][j] = __builtin_amdgcn_mfma_f32_16x16x32_bf16(af[i], bfr[j],
                                                                            acc[i][j], 0, 0, 0);
            } else {
#pragma unroll
                for (int i = 0; i < 4; ++i)
#pragma unroll
                    for (int j = 0; j < 4; ++j)
                        acc[i][j] = __builtin_amdgcn_mfma_f32_16x16x32_bf16(bfr[j], af[i],
                                                                            acc[i][j], 0, 0, 0);
            }
        }
        __syncthreads();
    }

    if (MODE == 1) {
        // C^T: row n = ...quad*4+r, col m = ...l15
#pragma unroll
        for (int i = 0; i < 4; ++i) {
            const int m = m0 + wm * 64 + i * 16 + l15;
#pragma unroll
            for (int j = 0; j < 4; ++j) {
                const int n = n0 + wn * 64 + j * 16 + quad * 4;
                f32x4 v = acc[i][j];
                *(float4*)&fO[(size_t)m * DM + n] = *(float4*)&v;
            }
        }
    } else if (isV) {
        // C: row m (=s) = ...quad*4+r, col n (=h,d) = ...l15
#pragma unroll
        for (int i = 0; i < 4; ++i) {
            const int m = m0 + wm * 64 + i * 16 + quad * 4;
            const int b = m >> 11, s0 = m & (SB - 1);
            // PV-fragment permutation of the 4-aligned group start:
            const int sp = (s0 & ~31) | (((s0 >> 2) & 3) << 3) | (((s0 >> 4) & 1) << 2);
#pragma unroll
            for (int j = 0; j < 4; ++j) {
                const int nv = (n0 - 2048) + wn * 64 + j * 16 + l15;
                const int h = nv >> 6, d = nv & 63;
                f16x2 a = __builtin_amdgcn_cvt_pkrtz(acc[i][j][0], acc[i][j][1]);
                f16x2 b2 = __builtin_amdgcn_cvt_pkrtz(acc[i][j][2], acc[i][j][3]);
                f16x4 o = {a.x, a.y, b2.x, b2.y};
                *(f16x4*)&vO[((size_t)((b * NH + h) * HD + d)) * SB + sp] = o;
            }
        }
    } else {
        // C^T: row n = ...quad*4+r, col m = ...l15
#pragma unroll
        for (int i = 0; i < 4; ++i) {
            const int m = m0 + wm * 64 + i * 16 + l15;
            const int b = m >> 11, s = m & (SB - 1);
#pragma unroll
            for (int j = 0; j < 4; ++j) {
                const int n = n0 + wn * 64 + j * 16 + quad * 4;
                const int seg = n >> 10;
                const int h = (n & 1023) >> 6, d0 = n & 63;
                const float sc = (seg == 0) ? QSCALE : 1.0f;
                bf16x4 o;
#pragma unroll
                for (int r = 0; r < 4; ++r) o[r] = f2bf(acc[i][j][r] * sc);
                short* dst = (seg == 0) ? qO : kO;
                *(bf16x4*)&dst[(((size_t)(b * NH + h) * SB + s) << 6) + d0] = o;
            }
        }
    }
}

// ---------------------------------------------------------------------------
// Flash attention v5.2: 64-row q-tiles paired (i, 31-i) -> 1024 uniform
// 34-step blocks (4/CU). idx&7 == bh&7 -> same-bh blocks share an XCD.
// LDS-staged double-buffered 64x64 K/V tiles (XOR-swizzled on the global
// source, global_load_lds width 16) + register-direct P^T (S^T trick).
// V comes pre-permuted (s' = quad*8 + parity*4 + j within 32-blocks) so a
// single ds_read_b128 yields the fragments for TWO adjacent st-blocks:
// V DS reads 16xb64 -> 8xb128 per step (DS-bound kernel: -14% DS).
// Scores pre-scaled by log2(e) -> exp2 softmax. No-max softmax (R2-R10).
// ---------------------------------------------------------------------------
__global__ __launch_bounds__(256) void attn_mfma(const short* __restrict__ Q,
                                                 const short* __restrict__ K,
                                                 const _Float16* __restrict__ VT,
                                                 short* __restrict__ ctx) {
    __shared__ short    sK[2][64 * 64];   // [buf][s][d]  bf16, swizzled  16 KB
    __shared__ _Float16 sV[2][64 * 64];   // [buf][d][s'] f16,  swizzled  16 KB

    const int t = threadIdx.x;
    const int lane = t & 63, w = t >> 6;
    const int l15 = lane & 15, quad = lane >> 4;
    const int idx = blockIdx.x;                       // 0..1023
    const int bh = ((idx >> 7) << 3) | (idx & 7);     // same-bh -> same XCD
    const int pair = (idx >> 3) & 15;
    const int b = bh >> 4, h = bh & 15;
    const size_t hb = (size_t)bh * SB * HD;
    const short* Qb = Q + hb;
    const short* Kb = K + hb;
    const _Float16* Vb = VT + hb;

    const int srow = t >> 3;          // 0..31
    const int sch  = t & 7;
    const int srow2 = srow + 32;
    const int swl = l15 & 7;          // reader-side XOR key

    auto stage = [&](int k0, int bbuf) {
        __builtin_amdgcn_global_load_lds(
            (const __attribute__((address_space(1))) unsigned*)
                (Kb + (size_t)(k0 + srow) * HD + ((sch ^ (srow & 7)) << 3)),
            (__attribute__((address_space(3))) unsigned*)&sK[bbuf][t << 3], 16, 0, 0);
        __builtin_amdgcn_global_load_lds(
            (const __attribute__((address_space(1))) unsigned*)
                (Kb + (size_t)(k0 + srow2) * HD + ((sch ^ (srow2 & 7)) << 3)),
            (__attribute__((address_space(3))) unsigned*)&sK[bbuf][(t + 256) << 3], 16, 0, 0);
        __builtin_amdgcn_global_load_lds(
            (const __attribute__((address_space(1))) unsigned*)
                (Vb + (size_t)srow * SB + k0 + ((sch ^ (srow & 7)) << 3)),
            (__attribute__((address_space(3))) unsigned*)&sV[bbuf][t << 3], 16, 0, 0);
        __builtin_amdgcn_global_load_lds(
            (const __attribute__((address_space(1))) unsigned*)
                (Vb + (size_t)srow2 * SB + k0 + ((sch ^ (srow2 & 7)) << 3)),
            (__attribute__((address_space(3))) unsigned*)&sV[bbuf][(t + 256) << 3], 16, 0, 0);
    };

#pragma unroll
    for (int ph = 0; ph < 2; ++ph) {
        const int qt = ph ? (31 - pair) : pair;
        const int qw = qt * 64 + w * 16;      // wave's 16 q-rows

        bf16x8 aq[2];
#pragma unroll
        for (int hh = 0; hh < 2; ++hh)
            aq[hh] = *(const bf16x8*)(Qb + (size_t)(qw + l15) * HD + hh * 32 + quad * 8);

        f32x4 O[4] = {};   // O^T[d=16dj+quad*4+r][q=qw+l15]
        float l_r = 0.f;

        __syncthreads();   // phase boundary: prior phase's LDS reads done
        stage(0, 0);

#pragma unroll 2
        for (int kt = 0; kt <= qt; ++kt) {
            __syncthreads();
            if (kt < qt) stage((kt + 1) * 64, (kt + 1) & 1);

            const int buf = kt & 1;
            const bool diag = (kt == qt);
            const short* sKb = &sK[buf][0];
            const _Float16* sVb = &sV[buf][0];

            // S^T: 64 s-rows x 16 q-cols (scores in log2 domain)
            f32x4 sc[4] = {};
#pragma unroll
            for (int st = 0; st < 4; ++st) {
                const int row = st * 16 + l15;
#pragma unroll
                for (int hh = 0; hh < 2; ++hh) {
                    bf16x8 kf = *(const bf16x8*)&sKb[(row << 6) +
                                                     (((hh * 4 + quad) ^ swl) << 3)];
                    sc[st] = __builtin_amdgcn_mfma_f32_16x16x32_bf16(kf, aq[hh], sc[st], 0, 0, 0);
                }
            }

            // exp2 -> P^T (registers) -> PV MFMA; V b128 covers 2 st-blocks
#pragma unroll
            for (int stp = 0; stp < 2; ++stp) {
                if (diag && stp * 2 > w) break;       // wave-uniform
                f16x8 vv[4];
                const int vch = ((stp * 4 + quad) ^ swl) << 3;
#pragma unroll
                for (int dj = 0; dj < 4; ++dj)
                    vv[dj] = *(const f16x8*)&sVb[((dj * 16 + l15) << 6) + vch];
#pragma unroll
                for (int half = 0; half < 2; ++half) {
                    const int st = stp * 2 + half;
                    if (diag && st > w) break;        // wave-uniform
                    float p[4];
                    if (!diag || st < w) {
#pragma unroll
                        for (int r = 0; r < 4; ++r) p[r] = __builtin_amdgcn_exp2f(sc[st][r]);
                    } else {  // st == w: partial triangle, s<=q <=> quad*4+r <= l15
#pragma unroll
                        for (int r = 0; r < 4; ++r)
                            p[r] = (quad * 4 + r <= l15) ? __builtin_amdgcn_exp2f(sc[st][r]) : 0.f;
                    }
                    l_r += (p[0] + p[1]) + (p[2] + p[3]);
                    f16x2 pa = __builtin_amdgcn_cvt_pkrtz(p[0], p[1]);
                    f16x2 pb = __builtin_amdgcn_cvt_pkrtz(p[2], p[3]);
                    f16x4 pf = {pa.x, pa.y, pb.x, pb.y};
#pragma unroll
                    for (int dj = 0; dj < 4; ++dj) {
                        f16x4 vfh;
                        if (half == 0)
                            vfh = __builtin_shufflevector(vv[dj], vv[dj], 0, 1, 2, 3);
                        else
                            vfh = __builtin_shufflevector(vv[dj], vv[dj], 4, 5, 6, 7);
                        O[dj] = __builtin_amdgcn_mfma_f32_16x16x16f16(vfh, pf, O[dj], 0, 0, 0);
                    }
                }
            }
        }

        // epilogue: reduce l across quads, write ctx[b][s][h*64+d]
        float l = l_r;
        l += __shfl_xor(l, 16);
        l += __shfl_xor(l, 32);
        const float inv = 1.f / l;
        const int q = qw + l15;
#pragma unroll
        for (int dj = 0; dj < 4; ++dj) {
            bf16x4 o;
#pragma unroll
            for (int r = 0; r < 4; ++r) o[r] = f2bf(O[dj][r] * inv);
            *(bf16x4*)&ctx[(size_t)(b * SB + q) * DM + h * HD + dj * 16 + quad * 4] = o;
        }
    }
}

extern "C" void kernel_launch(void* const* d_in, const int* in_sizes, int n_in,
                              void* d_out, int out_size, void* d_ws, size_t ws_size,
                              hipStream_t stream) {
    const float* x  = (const float*)d_in[0];
    const float* Wq = (const float*)d_in[1];
    const float* Wk = (const float*)d_in[2];
    const float* Wv = (const float*)d_in[3];
    const float* Wo = (const float*)d_in[4];
    float* out = (float*)d_out;

    const size_t NX = (size_t)MTOT * DM;   // 8,388,608
    short* xb   = (short*)d_ws;
    short* wall = xb + NX;        // QKV weights, BT layout, [3072][1024]
    short* wot  = wall + 3 * (size_t)NW;
    short* qb   = wot + NW;
    short* kb   = qb + NX;
    short* vtb  = kb + NX;        // f16 [b,h,d,s'] (PV-permuted)
    short* ctxb = vtb + NX;

    dim3 blk(256);
    cvt_all<<<4096 + 1024, blk, 0, stream>>>(x, Wq, Wk, Wv, Wo, xb, wall, wot);

    dim3 gqkv(MTOT / 128, 3072 / 128);
    mm64<0><<<gqkv, blk, 0, stream>>>(xb, wall, qb, kb, (_Float16*)vtb, nullptr);

    attn_mfma<<<dim3(1024), blk, 0, stream>>>(qb, kb, (const _Float16*)vtb, ctxb);

    dim3 gout(MTOT / 128, DM / 128);
    mm64<1><<<gout, blk, 0, stream>>>(ctxb, wot, nullptr, nullptr, nullptr, out);
}